// Round 6
// baseline (25752.634 us; speedup 1.0000x reference)
//
#include <hip/hip_runtime.h>
#include <cmath>

#define BN 2048
#define DXC 256
#define DZC 64
#define INV_B (1.0f/2048.0f)
#define NITER 50
#define NBLK 256

typedef unsigned short ushortT;
typedef __attribute__((ext_vector_type(8))) short s8;
typedef __attribute__((ext_vector_type(4))) float f4;

// ---- workspace layout (float offsets) ----
#define OFF_SH   ((size_t)0)          // scratch: UPb bf16 (2.10M f) / VP f32 stride-68 (2.23M f)
#define OFF_XT   ((size_t)3670016)    // f32 xT[256][2048]
#define OFF_KB   ((size_t)4194304)    // ushort Kb[j][i]
#define OFF_M1B  ((size_t)6291456)    // ushort M1b[2048][2048]
#define OFF_UB   ((size_t)8388608)    // ushort Ub[2048][256]
#define OFF_XB   ((size_t)8650752)    // ushort xb[2048][256]
#define OFF_XRT  ((size_t)8912896)    // ushort xrbT[256][2048]
#define OFF_VB   ((size_t)9175040)    // ushort Vb[2048][64]
#define OFF_ZB   ((size_t)9240576)    // ushort zb[2048][64]
#define OFF_ZTB  ((size_t)9306112)    // ushort zTb[128][2048]
#define OFF_V64  ((size_t)9437184)
#define OFF_V65  ((size_t)9439232)
#define OFF_SQX  ((size_t)9441280)
#define OFF_SQZ  ((size_t)9443328)
#define OFF_CX   ((size_t)9445376)
#define OFF_CZ   ((size_t)9447424)
#define OFF_R    ((size_t)9449472)
#define OFF_C    ((size_t)9451520)
#define OFF_RSQX ((size_t)9453568)
#define OFF_RSQZ ((size_t)9455616)
#define OFF_U6   ((size_t)9457664)
#define OFF_U7   ((size_t)9459712)
#define OFF_ACC  ((size_t)9461760)    // [5][4][2048] f32: round 0 = rowsum, 1..4 = r-round partials
#define OFF_RMX  ((size_t)9527296)
#define OFF_SCAL ((size_t)9529344)
// scal: 0=sum Craw_x, 1=sum Craw_z, 2=sx, 3=sz, 4=sum constx, 5=sum constz,
//       6=cross_term, 7=reg_sum, 8=sum sqx, 16/17=global barrier words

__device__ __forceinline__ float wave_sum(float v){
  for (int o=32;o;o>>=1) v += __shfl_down(v,o);
  return v;
}
__device__ __forceinline__ void fma16(float (&acc)[4][4], const float* a4, const float* b4){
  #pragma unroll
  for (int m=0;m<4;m++)
    #pragma unroll
    for (int n=0;n<4;n++)
      acc[m][n] = fmaf(a4[m], b4[n], acc[m][n]);
}
__device__ __forceinline__ unsigned encf(float f){
  unsigned u = __float_as_uint(f);
  return (u & 0x80000000u) ? ~u : (u | 0x80000000u);
}
__device__ __forceinline__ float decf(unsigned u){
  return (u & 0x80000000u) ? __uint_as_float(u & 0x7fffffffu) : __uint_as_float(~u);
}
__device__ __forceinline__ ushortT f2bf(float f){
  unsigned u = __float_as_uint(f);
  return (ushortT)((u + 0x7FFFu + ((u>>16)&1u)) >> 16);
}
__device__ __forceinline__ float bf2f(ushortT v){
  return __uint_as_float(((unsigned)v)<<16);
}
__device__ __forceinline__ void gload16(const void* g, void* l){
  __builtin_amdgcn_global_load_lds((const __attribute__((address_space(1))) void*)g,
                                   (__attribute__((address_space(3))) void*)l, 16, 0, 0);
}

// hand-rolled sense-reversing grid barrier (device-scope atomics; all 256 blocks resident)
__device__ __forceinline__ void gbar(float* ws){
  unsigned* bar = (unsigned*)(ws + OFF_SCAL + 16);
  __syncthreads();
  if (threadIdx.x == 0){
    __threadfence();
    unsigned g = __hip_atomic_load(bar+1, __ATOMIC_RELAXED, __HIP_MEMORY_SCOPE_AGENT);
    unsigned arr = __hip_atomic_fetch_add(bar, 1u, __ATOMIC_ACQ_REL, __HIP_MEMORY_SCOPE_AGENT);
    if (arr == NBLK-1u){
      __hip_atomic_store(bar, 0u, __ATOMIC_RELAXED, __HIP_MEMORY_SCOPE_AGENT);
      __hip_atomic_fetch_add(bar+1, 1u, __ATOMIC_RELEASE, __HIP_MEMORY_SCOPE_AGENT);
    } else {
      while (__hip_atomic_load(bar+1, __ATOMIC_RELAXED, __HIP_MEMORY_SCOPE_AGENT) == g)
        __builtin_amdgcn_s_sleep(2);
    }
    __threadfence();
  }
  __syncthreads();
}

// ---------------- MFMA core: MRxNR tile (4 waves/256 thr), A[M][K] bf16, BT[N][K] bf16 ----
template<int MR, int NR>
__device__ __forceinline__ void gemm_core(const ushortT* __restrict__ A, int ldA,
                                          const ushortT* __restrict__ B, int ldB,
                                          int m0, int n0, int kstart, int ksteps,
                                          ushortT* As, ushortT* Bs, f4 (&acc)[4][4]){
  const int t = threadIdx.x, w = t>>6, lane = t&63;
  constexpr int WC = NR/64;
  const int wr = w / WC, wc = w % WC;
  const int lrow = lane&15, quad = lane>>4;
  constexpr int RA = MR/4, QA = RA/8;
  constexpr int RB = NR/4, QB = RB/8;
  const int r0A = w*RA, r0B = w*RB;
  const int srow = lane>>3, schunk = (lane&7)*8;
  for (int ks = 0; ks < ksteps; ks++){
    const int kk0 = kstart + ks*64;
    __syncthreads();
    #pragma unroll
    for (int q=0;q<QA;q++)
      gload16(A + (size_t)(m0 + r0A + q*8 + srow)*ldA + kk0 + schunk, As + (r0A + q*8)*64);
    #pragma unroll
    for (int q=0;q<QB;q++)
      gload16(B + (size_t)(n0 + r0B + q*8 + srow)*ldB + kk0 + schunk, Bs + (r0B + q*8)*64);
    __syncthreads();
    #pragma unroll
    for (int kk=0;kk<2;kk++){
      s8 af[4], bfr[4];
      #pragma unroll
      for (int tm=0;tm<4;tm++)
        af[tm] = *(const s8*)(As + (wr*64 + tm*16 + lrow)*64 + kk*32 + quad*8);
      #pragma unroll
      for (int tn=0;tn<4;tn++)
        bfr[tn] = *(const s8*)(Bs + (wc*64 + tn*16 + lrow)*64 + kk*32 + quad*8);
      #pragma unroll
      for (int tm=0;tm<4;tm++)
        #pragma unroll
        for (int tn=0;tn<4;tn++)
          acc[tm][tn] = __builtin_amdgcn_mfma_f32_16x16x32_bf16(af[tm], bfr[tn], acc[tm][tn], 0,0,0);
    }
  }
}

// ---------------- setup kernels ----------------

__global__ __launch_bounds__(256) void k_zero(float* __restrict__ ws){
  int t = blockIdx.x*256 + threadIdx.x;
  if (t < BN) { ws[OFF_RSQX + t] = 0.f; ws[OFF_RSQZ + t] = 0.f; }
  if (t < 64) ws[OFF_SCAL + t] = 0.f;
}

__global__ __launch_bounds__(64) void k_sq_x(const float* __restrict__ x, float* __restrict__ ws){
  int row = blockIdx.x, t = threadIdx.x;
  const float* xr = x + (size_t)row*DXC;
  float s = 0.f;
  for (int k = t; k < DXC; k += 64) { float v = xr[k]; s += v*v; }
  s = wave_sum(s);
  if (t == 0) { ws[OFF_SQX + row] = s; atomicAdd(&ws[OFF_SCAL+8], s); }
}

__global__ __launch_bounds__(64) void k_sq_z(const float* __restrict__ z, float* __restrict__ ws){
  int row = blockIdx.x, t = threadIdx.x;
  float v = (t < DZC) ? z[(size_t)row*DZC + t] : 0.f;
  float s = wave_sum(v*v);
  if (t == 0) ws[OFF_SQZ + row] = s;
}

template<int D>
__global__ __launch_bounds__(64) void k_stats(const float* __restrict__ P,
                                              const float* __restrict__ sq,
                                              float* __restrict__ ws, int sumidx,
                                              float* __restrict__ rowsq){
  __shared__ __align__(16) float As[32][36];
  __shared__ __align__(16) float Bs[32][36];
  const int i0 = blockIdx.x*32, j0 = blockIdx.y*32;
  const int t = threadIdx.x, tr = t&7, tc = t>>3;
  float acc[4][4] = {};
  for (int k0 = 0; k0 < D; k0 += 32) {
    for (int l = t; l < 1024; l += 64) {
      const int rr = l>>5, cc = l&31;
      As[cc][rr] = P[(size_t)(i0+rr)*D + (k0+cc)];
      Bs[cc][rr] = P[(size_t)(j0+rr)*D + (k0+cc)];
    }
    __syncthreads();
    #pragma unroll
    for (int kk = 0; kk < 32; kk++) {
      float a[4], b[4];
      *(float4*)a = *(const float4*)&As[kk][tr*4];
      *(float4*)b = *(const float4*)&Bs[kk][tc*4];
      fma16(acc, a, b);
    }
    __syncthreads();
  }
  float sqi[4], sqj[4];
  #pragma unroll
  for (int m=0;m<4;m++) sqi[m] = sq[i0+tr*4+m];
  #pragma unroll
  for (int n=0;n<4;n++) sqj[n] = sq[j0+tc*4+n];
  float tot = 0.f; float rs[4] = {0.f,0.f,0.f,0.f};
  #pragma unroll
  for (int m=0;m<4;m++)
    #pragma unroll
    for (int n=0;n<4;n++) {
      float raw = sqi[m] + sqj[n] - 2.f*acc[m][n];
      float cr = fmaxf(raw, 0.f);
      tot += cr;
      rs[m] += cr*cr;
    }
  float v = wave_sum(tot);
  if (t==0) atomicAdd(&ws[OFF_SCAL+sumidx], v);
  #pragma unroll
  for (int m=0;m<4;m++){
    float x2 = rs[m];
    x2 += __shfl_down(x2,32); x2 += __shfl_down(x2,16); x2 += __shfl_down(x2,8);
    if (tc==0) atomicAdd(&rowsq[i0+tr*4+m], x2);
  }
}

__global__ __launch_bounds__(256) void k_s3(const float* __restrict__ z, float* __restrict__ ws){
  int j = blockIdx.x*256 + threadIdx.x;
  float mx = ws[OFF_SCAL+0] / ((float)BN*(float)BN);
  float sx = 1.f/(mx + 1e-8f);
  float mz = ws[OFF_SCAL+1] / ((float)BN*(float)BN);
  float sz = 1.f/(mz + 1e-8f);
  if (j == 0) { ws[OFF_SCAL+2] = sx; ws[OFF_SCAL+3] = sz; }
  if (j < BN) {
    float cx = ws[OFF_RSQX+j]*sx*sx*INV_B;
    float cz = ws[OFF_RSQZ+j]*sz*sz*INV_B;
    ws[OFF_CX+j] = cx; ws[OFF_CZ+j] = cz;
    atomicAdd(&ws[OFF_SCAL+4], cx);
    atomicAdd(&ws[OFF_SCAL+5], cz);
    ws[OFF_R+j] = INV_B; ws[OFF_C+j] = 1.f;
    float msx = ws[OFF_SCAL+8]*INV_B;
    ws[OFF_U6+j] = 1.f;
    ws[OFF_U7+j] = msx;
    ushortT* zb  = (ushortT*)(ws + OFF_ZB);
    ushortT* zTb = (ushortT*)(ws + OFF_ZTB);
    for (int m=0;m<DZC;m++){
      ushortT v = f2bf(z[(size_t)j*DZC + m]);
      zb[(size_t)j*DZC + m] = v;
      zTb[(size_t)m*BN + j] = v;
    }
    zTb[(size_t)64*BN + j] = 0x3F80;               // 1.0
    zTb[(size_t)65*BN + j] = f2bf(ws[OFF_SQZ+j]);  // sqz
    for (int m=66;m<128;m++) zTb[(size_t)m*BN + j] = 0;
  }
}

__global__ __launch_bounds__(256) void k_cvt_x(const float* __restrict__ x, float* __restrict__ ws){
  int idx = blockIdx.x*256 + threadIdx.x;
  ((ushortT*)(ws + OFF_XB))[idx] = f2bf(x[idx]);
}

__global__ __launch_bounds__(256) void k_fillKb(float* __restrict__ ws){
  size_t idx = (size_t)blockIdx.x*256 + threadIdx.x;
  uint4 v = {0x3F803F80u, 0x3F803F80u, 0x3F803F80u, 0x3F803F80u};
  ((uint4*)(ws + OFF_KB))[idx] = v;
}

// XT[k][i] = x[i][k] (f32 transpose, once)
__global__ __launch_bounds__(256) void k_xt(const float* __restrict__ x, float* __restrict__ ws){
  __shared__ float tr[32][65];
  const int i0 = blockIdx.x*64, k0 = blockIdx.y*32;
  const int t = threadIdx.x;
  #pragma unroll
  for (int s=0;s<8;s++){
    int idx = t + s*256; int il = idx>>5, kl = idx&31;
    tr[kl][il] = x[(size_t)(i0+il)*DXC + k0+kl];
  }
  __syncthreads();
  float* XT = ws + OFF_XT;
  #pragma unroll
  for (int s=0;s<8;s++){
    int idx = t + s*256; int kl = idx>>6, il = idx&63;
    XT[(size_t)(k0+kl)*BN + i0+il] = tr[kl][il];
  }
}

// initial xrbT = bf16(XT * INV_B)
__global__ __launch_bounds__(256) void k_xr0(float* __restrict__ ws){
  int idx = blockIdx.x*256 + threadIdx.x;
  ((ushortT*)(ws + OFF_XRT))[idx] = f2bf(ws[OFF_XT + idx] * INV_B);
}

// ---------------- THE persistent kernel: 50 iterations + final cross (software grid barrier) ----------------

__global__ __launch_bounds__(256, 1) void k_sink(float* __restrict__ ws){
  __shared__ __align__(16) char smem[40960];
  ushortT* As64  = (ushortT*)smem;               // k1: 64x64
  ushortT* Bs256 = (ushortT*)(smem + 8192);      // k1: 256x64
  ushortT* As128 = (ushortT*)smem;               // 128-tiles
  ushortT* Bs128 = (ushortT*)(smem + 16384);
  float*   red1  = (float*)smem;                 // normalize: 8*256
  float*   red2  = (float*)(smem + 8192);
  float*   ccs   = (float*)(smem + 16384);       // 8 floats

  const int bid = blockIdx.x, t = threadIdx.x;
  const int w = t>>6, lane = t&63;
  const int lrow = lane&15, quad = lane>>4;
  const int aln = bid&3;                          // atomic contention lane

  for (int it = 0; it <= NITER; it++){
    const bool fin = (it == NITER);

    // ---- k1: UPb[sp][j][k] = bf16(sum_{i in split} Kb[j,i]*xrbT[k,i]) ----
    {
      const int m0 = (bid&31)*64, sp = bid>>5;
      f4 acc[4][4] = {};
      gemm_core<64,256>((const ushortT*)(ws+OFF_KB), BN, (const ushortT*)(ws+OFF_XRT), BN,
                        m0, 0, sp*256, 4, As64, Bs256, acc);
      ushortT* __restrict__ UPb = (ushortT*)(ws + OFF_SH) + (size_t)sp*BN*DXC;
      const int wc4 = w&3;
      #pragma unroll
      for (int tm=0;tm<4;tm++)
        #pragma unroll
        for (int tn=0;tn<4;tn++)
          #pragma unroll
          for (int rg=0;rg<4;rg++)
            UPb[(size_t)(m0+tm*16+quad*4+rg)*DXC + wc4*64+tn*16+lrow] = f2bf(acc[tm][tn][rg]);
    }
    gbar(ws);

    // ---- k1_red: Ub[j][k] = bf16(c_j * sum_sp UPb) ----
    {
      const ushortT* __restrict__ UPb = (const ushortT*)(ws + OFF_SH);
      ushortT* __restrict__ Ub = (ushortT*)(ws + OFF_UB);
      #pragma unroll
      for (int s=0;s<8;s++){
        int idx = bid*2048 + t + s*256;
        int j = idx >> 8;
        float sum = 0.f;
        #pragma unroll
        for (int sp=0;sp<8;sp++) sum += bf2f(UPb[(size_t)sp*BN*DXC + idx]);
        Ub[idx] = f2bf(sum * ws[OFF_C + j]);
      }
    }
    gbar(ws);

    // ---- k2: M1b ----
    {
      const int m0 = (bid&15)*128, n0 = (bid>>4)*128;
      f4 acc[4][4] = {};
      gemm_core<128,128>((const ushortT*)(ws+OFF_XB), DXC, (const ushortT*)(ws+OFF_UB), DXC,
                         m0, n0, 0, 4, As128, Bs128, acc);
      const float sx = ws[OFF_SCAL+2];
      const int wr = w>>1, wc = w&1;
      ushortT* __restrict__ M1 = (ushortT*)(ws + OFF_M1B);
      #pragma unroll
      for (int tn=0;tn<4;tn++){
        const int j = n0 + wc*64 + tn*16 + lrow;
        const float u6 = ws[OFF_U6+j], u7 = ws[OFF_U7+j];
        #pragma unroll
        for (int tm=0;tm<4;tm++)
          #pragma unroll
          for (int rg=0;rg<4;rg++){
            const int i = m0 + wr*64 + tm*16 + quad*4 + rg;
            M1[(size_t)i*BN + j] = f2bf(sx*(ws[OFF_SQX+i]*u6 + u7 - 2.f*acc[tm][tn][rg]));
          }
      }
    }
    gbar(ws);

    // ---- k3: VP[sp][i][m] (stride 68) ----
    {
      const int m0 = (bid&15)*128, sp = bid>>4;
      f4 acc[4][4] = {};
      gemm_core<128,128>((const ushortT*)(ws+OFF_M1B), BN, (const ushortT*)(ws+OFF_ZTB), BN,
                         m0, 0, sp*128, 2, As128, Bs128, acc);
      float* __restrict__ VP = ws + OFF_SH + (size_t)sp*BN*68;
      const int wr = w>>1, wc = w&1;
      #pragma unroll
      for (int tn=0;tn<4;tn++){
        const int col = wc*64 + tn*16 + lrow;
        if (col < 66)
          #pragma unroll
          for (int tm=0;tm<4;tm++)
            #pragma unroll
            for (int rg=0;rg<4;rg++)
              VP[(size_t)(m0+wr*64+tm*16+quad*4+rg)*68 + col] = acc[tm][tn][rg];
      }
    }
    gbar(ws);

    // ---- k3_red + zero RMX/ACC ----
    {
      int gidx = bid*256 + t;
      if (gidx < BN) ((unsigned*)(ws + OFF_RMX))[gidx] = 0u;
      if (gidx < 5*4*BN) ws[OFF_ACC + gidx] = 0.f;
      ushortT* __restrict__ Vb = (ushortT*)(ws + OFF_VB);
      for (int idx = gidx; idx < BN*68; idx += 65536){
        int i = idx/68, m = idx - i*68;
        if (m < 66){
          float s = 0.f;
          #pragma unroll
          for (int sp=0;sp<16;sp++) s += ws[OFF_SH + (size_t)sp*BN*68 + idx];
          if (m < 64)       Vb[(size_t)i*64 + m] = f2bf(s);
          else if (m == 64) ws[OFF_V64 + i] = s;
          else              ws[OFF_V65 + i] = s;
        }
      }
    }
    gbar(ws);

    // ---- k4: cross GEMM (acc kept in registers across barriers) ----
    const int m0c = (bid&15)*128, n0c = (bid>>4)*128;   // m=j, n=i
    f4 accc[4][4] = {};
    gemm_core<128,128>((const ushortT*)(ws+OFF_ZB), DZC, (const ushortT*)(ws+OFF_VB), DZC,
                       m0c, n0c, 0, 1, As128, Bs128, accc);
    const float sz = ws[OFF_SCAL+3];
    const int wr = w>>1, wc = w&1;

    if (!fin){
      // row-max of expo
      {
        unsigned* __restrict__ rmx = (unsigned*)(ws + OFF_RMX);
        #pragma unroll
        for (int tn=0;tn<4;tn++){
          const int i = n0c + wc*64 + tn*16 + lrow;
          const float v64 = ws[OFF_V64+i], v65 = ws[OFF_V65+i], cx = ws[OFF_CX+i];
          float mx = -3.4e38f;
          #pragma unroll
          for (int tm=0;tm<4;tm++)
            #pragma unroll
            for (int rg=0;rg<4;rg++){
              const int j = m0c + wr*64 + tm*16 + quad*4 + rg;
              float cross = sz*(v65 + v64*ws[OFF_SQZ+j] - 2.f*accc[tm][tn][rg]);
              float expo = 2.f*cross - cx - ws[OFF_CZ+j];
              mx = fmaxf(mx, expo);
            }
          mx = fmaxf(mx, __shfl_down(mx,32));
          mx = fmaxf(mx, __shfl_down(mx,16));
          if (quad == 0) atomicMax(&rmx[i], encf(mx));
        }
      }
      gbar(ws);
      // k5exp: reuse accc — Kb write + rowsum atomicAdd into ACC[0][aln]
      {
        ushortT* __restrict__ Kb = (ushortT*)(ws + OFF_KB);
        const unsigned* __restrict__ rmx = (const unsigned*)(ws + OFF_RMX);
        #pragma unroll
        for (int tn=0;tn<4;tn++){
          const int i = n0c + wc*64 + tn*16 + lrow;
          const float v64 = ws[OFF_V64+i], v65 = ws[OFF_V65+i], cx = ws[OFF_CX+i];
          const float Mi = decf(rmx[i]);
          float s = 0.f;
          #pragma unroll
          for (int tm=0;tm<4;tm++)
            #pragma unroll
            for (int rg=0;rg<4;rg++){
              const int j = m0c + wr*64 + tm*16 + quad*4 + rg;
              float cross = sz*(v65 + v64*ws[OFF_SQZ+j] - 2.f*accc[tm][tn][rg]);
              float expo = 2.f*cross - cx - ws[OFF_CZ+j];
              ushortT vv = f2bf(__expf(expo - Mi));
              Kb[(size_t)j*BN + i] = vv;
              s += bf2f(vv);
            }
          s += __shfl_down(s,32);
          s += __shfl_down(s,16);
          if (quad == 0) atomicAdd(&ws[OFF_ACC + (size_t)aln*BN + i], s);
        }
      }
      gbar(ws);

      // ---- normalize: block owns rows j0..j0+7 of Kb, pinned in registers ----
      const int j0 = bid*8;
      float rv[8];
      #pragma unroll
      for (int q=0;q<8;q++){
        int i = t + q*256;
        float s0 = ws[OFF_ACC+i] + ws[OFF_ACC+BN+i] + ws[OFF_ACC+2*BN+i] + ws[OFF_ACC+3*BN+i];
        rv[q] = INV_B/(s0 + 1e-8f);
      }
      float v[8][8];
      {
        const ushortT* __restrict__ Kbp = (const ushortT*)(ws + OFF_KB);
        #pragma unroll
        for (int jj=0;jj<8;jj++)
          #pragma unroll
          for (int q=0;q<8;q++)
            v[jj][q] = bf2f(Kbp[(size_t)(j0+jj)*BN + t + q*256]);
      }
      for (int n=0;n<5;n++){
        __syncthreads();
        #pragma unroll
        for (int jj=0;jj<8;jj++){
          float s1 = 0.f, s2 = 0.f;
          if (n == 4){
            #pragma unroll
            for (int q=0;q<8;q++){ float kv = v[jj][q]*rv[q]; s1 += kv; s2 += kv*ws[OFF_SQX + t+q*256]; }
          } else {
            #pragma unroll
            for (int q=0;q<8;q++) s1 += v[jj][q]*rv[q];
          }
          red1[jj*256 + t] = s1;
          red2[jj*256 + t] = s2;
        }
        __syncthreads();
        const int g = t>>5, l = t&31;
        float a = 0.f, b = 0.f;
        #pragma unroll
        for (int k=0;k<8;k++) a += red1[g*256 + l + k*32];
        if (n == 4)
          #pragma unroll
          for (int k=0;k<8;k++) b += red2[g*256 + l + k*32];
        #pragma unroll
        for (int o=16;o;o>>=1){
          a += __shfl_xor(a, o);
          if (n == 4) b += __shfl_xor(b, o);
        }
        if (l == 0){
          float cn;
          if (n == 0) cn = INV_B/(a + 1e-8f);
          else { float cj = ccs[g]; cn = cj*INV_B/(cj*a + 1e-8f); }
          ccs[g] = cn;
          if (n == 4){
            const int j = j0 + g;
            ws[OFF_C+j]  = cn;
            ws[OFF_U6+j] = cn*a;
            ws[OFF_U7+j] = cn*b;
          }
        }
        __syncthreads();
        if (n < 4){
          float cl[8];
          #pragma unroll
          for (int jj=0;jj<8;jj++) cl[jj] = ccs[jj];
          const size_t ro = OFF_ACC + (size_t)((1+n)*4 + aln)*BN;
          #pragma unroll
          for (int q=0;q<8;q++){
            float p = 0.f;
            #pragma unroll
            for (int jj=0;jj<8;jj++) p += v[jj][q]*cl[jj];
            atomicAdd(&ws[ro + t + q*256], p);
          }
          gbar(ws);
          const size_t rr = OFF_ACC + (size_t)((1+n)*4)*BN;
          #pragma unroll
          for (int q=0;q<8;q++){
            int i = t + q*256;
            float s0 = ws[rr+i] + ws[rr+BN+i] + ws[rr+2*BN+i] + ws[rr+3*BN+i];
            float ri = rv[q];
            rv[q] = ri*INV_B/(ri*s0 + 1e-8f);
          }
        }
      }
      // tail: write next-iteration xrbT (block owns k-row bid) and R (block 0)
      {
        const float* __restrict__ XTp = ws + OFF_XT + (size_t)bid*BN;
        ushortT* __restrict__ XRT = (ushortT*)(ws + OFF_XRT) + (size_t)bid*BN;
        #pragma unroll
        for (int q=0;q<8;q++) XRT[t + q*256] = f2bf(XTp[t + q*256]*rv[q]);
      }
      if (bid == 0){
        #pragma unroll
        for (int q=0;q<8;q++) ws[OFF_R + t + q*256] = rv[q];
      }
    } else {
      // ---- final cross_term ----
      const ushortT* __restrict__ Kb = (const ushortT*)(ws + OFF_KB);
      float s = 0.f;
      #pragma unroll
      for (int tn=0;tn<4;tn++){
        const int i = n0c + wc*64 + tn*16 + lrow;
        const float v64 = ws[OFF_V64+i], v65 = ws[OFF_V65+i], ri = ws[OFF_R+i];
        #pragma unroll
        for (int tm=0;tm<4;tm++)
          #pragma unroll
          for (int rg=0;rg<4;rg++){
            const int j = m0c + wr*64 + tm*16 + quad*4 + rg;
            float cross = sz*(v65 + v64*ws[OFF_SQZ+j] - 2.f*accc[tm][tn][rg]);
            float tij = ri * bf2f(Kb[(size_t)j*BN + i]) * ws[OFF_C+j];
            s += cross*tij;
          }
      }
      s = wave_sum(s);
      if (lane == 0) atomicAdd(&ws[OFF_SCAL+6], s);
    }
    gbar(ws);
  }
}

// ---------------- reg loss + finalize ----------------

__global__ __launch_bounds__(64) void k_reg(const float* __restrict__ z, const float* __restrict__ y,
                                            float* __restrict__ ws){
  __shared__ __align__(16) float As[32][36];
  __shared__ __align__(16) float Bs[32][36];
  const int i0 = blockIdx.x*32, j0 = blockIdx.y*32;
  const int t = threadIdx.x, tr = t&7, tc = t>>3;
  float acc[4][4] = {};
  for (int k0=0; k0<DZC; k0+=32){
    for (int l=t;l<1024;l+=64){
      const int rr=l>>5, cc=l&31;
      As[cc][rr] = z[(size_t)(i0+rr)*DZC + (k0+cc)];
      Bs[cc][rr] = z[(size_t)(j0+rr)*DZC + (k0+cc)];
    }
    __syncthreads();
    #pragma unroll
    for (int kk=0;kk<32;kk++){
      float a[4], b[4];
      *(float4*)a = *(const float4*)&As[kk][tr*4];
      *(float4*)b = *(const float4*)&Bs[kk][tc*4];
      fma16(acc, a, b);
    }
    __syncthreads();
  }
  const float sz = ws[OFF_SCAL+3];
  float sqi[4], yi[4];
  #pragma unroll
  for (int m=0;m<4;m++){ int i=i0+tr*4+m; sqi[m]=ws[OFF_SQZ+i]; yi[m]=y[i]; }
  float sqj[4], yj[4];
  #pragma unroll
  for (int n=0;n<4;n++){ int j=j0+tc*4+n; sqj[n]=ws[OFF_SQZ+j]; yj[n]=y[j]; }
  float s = 0.f;
  #pragma unroll
  for (int m=0;m<4;m++)
    #pragma unroll
    for (int n=0;n<4;n++){
      int i = i0+tr*4+m, j = j0+tc*4+n;
      float raw = sqi[m] + sqj[n] - 2.f*acc[m][n];
      float cz = sz*fmaxf(raw, 0.f);
      float zd = fmaxf(cz, 1e-4f);
      float d = logf(fabsf(yi[m]-yj[n]) + 1e-6f) - logf(zd + 1e-6f);
      if (i != j) s += d*d;
    }
  s = wave_sum(s);
  if (t==0) atomicAdd(&ws[OFF_SCAL+7], s);
}

__global__ void k_finalize(float* __restrict__ ws, float* __restrict__ out){
  float gw = ws[OFF_SCAL+4]*INV_B + ws[OFF_SCAL+5]*INV_B - 2.f*ws[OFF_SCAL+6];
  gw = fmaxf(gw, 0.f);
  float reg = ws[OFF_SCAL+7] / ((float)BN*(float)(BN-1));
  out[0] = gw + reg;
}

// ---------------- host ----------------

extern "C" void kernel_launch(void* const* d_in, const int* in_sizes, int n_in,
                              void* d_out, int out_size, void* d_ws, size_t ws_size,
                              hipStream_t stream){
  (void)in_sizes; (void)n_in; (void)out_size; (void)ws_size;
  const float* x = (const float*)d_in[0];
  const float* z = (const float*)d_in[1];
  const float* y = (const float*)d_in[2];
  float* out = (float*)d_out;
  float* ws = (float*)d_ws;

  hipLaunchKernelGGL(k_zero, dim3(8), dim3(256), 0, stream, ws);
  hipLaunchKernelGGL(k_sq_x, dim3(BN), dim3(64), 0, stream, x, ws);
  hipLaunchKernelGGL(k_sq_z, dim3(BN), dim3(64), 0, stream, z, ws);
  hipLaunchKernelGGL(HIP_KERNEL_NAME(k_stats<DXC>), dim3(64,64), dim3(64), 0, stream,
                     x, ws+OFF_SQX, ws, 0, ws+OFF_RSQX);
  hipLaunchKernelGGL(HIP_KERNEL_NAME(k_stats<DZC>), dim3(64,64), dim3(64), 0, stream,
                     z, ws+OFF_SQZ, ws, 1, ws+OFF_RSQZ);
  hipLaunchKernelGGL(k_s3, dim3(8), dim3(256), 0, stream, z, ws);
  hipLaunchKernelGGL(k_cvt_x, dim3(2048), dim3(256), 0, stream, x, ws);
  hipLaunchKernelGGL(k_fillKb, dim3(2048), dim3(256), 0, stream, ws);
  hipLaunchKernelGGL(k_xt, dim3(32,8), dim3(256), 0, stream, x, ws);
  hipLaunchKernelGGL(k_xr0, dim3(2048), dim3(256), 0, stream, ws);

  hipLaunchKernelGGL(k_sink, dim3(NBLK), dim3(256), 0, stream, ws);

  hipLaunchKernelGGL(k_reg, dim3(64,64), dim3(64), 0, stream, z, y, ws);
  hipLaunchKernelGGL(k_finalize, dim3(1), dim3(1), 0, stream, ws, out);
}

// Round 7
// 5472.215 us; speedup vs baseline: 4.7061x; 4.7061x over previous
//
#include <hip/hip_runtime.h>
#include <cmath>

#define BN 2048
#define DXC 256
#define DZC 64
#define INV_B (1.0f/2048.0f)
#define NITER 50

typedef unsigned short ushortT;
typedef __attribute__((ext_vector_type(8))) short s8;
typedef __attribute__((ext_vector_type(4))) float f4;

// ---- workspace layout (float offsets), total ~24.8 MB ----
#define OFF_UPT  ((size_t)0)        // ushort[8][256][2048] U^T split-K partials
#define OFF_XT   ((size_t)2097152)  // f32 [256][2048]
#define OFF_KB   ((size_t)2621440)  // ushort Kb[j][i]
#define OFF_UTB  ((size_t)4718592)  // ushort[384][2048]; rows 0..255=U^T(c-folded), 256=u6, 257=u7, 258+=0
#define OFF_WTP  ((size_t)5111808)  // f32[4][128][384] W^T split-K partials
#define OFF_WTB  ((size_t)5308416)  // ushort[128][384] W^T bf16 (rows m, cols k)
#define OFF_A6   ((size_t)5332992)  // f32[128]
#define OFF_A7   ((size_t)5333120)  // f32[128]
#define OFF_XB   ((size_t)5333248)  // ushort[2048][256]
#define OFF_XRT  ((size_t)5595392)  // ushort[256][2048] r-weighted X^T
#define OFF_VB   ((size_t)5857536)  // ushort[2048][64]
#define OFF_ZB   ((size_t)5923072)  // ushort[2048][64]
#define OFF_ZTB  ((size_t)5988608)  // ushort[128][2048] (rows 64=1.0, 65=sqz, 66..127=0)
#define OFF_V64  ((size_t)6119680)
#define OFF_V65  ((size_t)6121728)
#define OFF_SQX  ((size_t)6123776)
#define OFF_SQZ  ((size_t)6125824)
#define OFF_CX   ((size_t)6127872)
#define OFF_CZ   ((size_t)6129920)
#define OFF_R    ((size_t)6131968)  // f32[2][2048] double-buffered r
#define OFF_C    ((size_t)6136064)
#define OFF_RSQX ((size_t)6138112)
#define OFF_RSQZ ((size_t)6140160)
#define OFF_U6   ((size_t)6142208)
#define OFF_U7   ((size_t)6144256)
#define OFF_ACC  ((size_t)6146304)  // f32[5][4][2048] round accumulators
#define OFF_RMX  ((size_t)6187264)
#define OFF_SCAL ((size_t)6189312)
// scal: 0=sum Craw_x, 1=sum Craw_z, 2=sx, 3=sz, 4=sum constx, 5=sum constz,
//       6=cross_term, 7=reg_sum, 8=sum sqx

__device__ __forceinline__ float wave_sum(float v){
  for (int o=32;o;o>>=1) v += __shfl_down(v,o);
  return v;
}
__device__ __forceinline__ void fma16(float (&acc)[4][4], const float* a4, const float* b4){
  #pragma unroll
  for (int m=0;m<4;m++)
    #pragma unroll
    for (int n=0;n<4;n++)
      acc[m][n] = fmaf(a4[m], b4[n], acc[m][n]);
}
__device__ __forceinline__ unsigned encf(float f){
  unsigned u = __float_as_uint(f);
  return (u & 0x80000000u) ? ~u : (u | 0x80000000u);
}
__device__ __forceinline__ float decf(unsigned u){
  return (u & 0x80000000u) ? __uint_as_float(u & 0x7fffffffu) : __uint_as_float(~u);
}
__device__ __forceinline__ ushortT f2bf(float f){
  unsigned u = __float_as_uint(f);
  return (ushortT)((u + 0x7FFFu + ((u>>16)&1u)) >> 16);
}
__device__ __forceinline__ float bf2f(ushortT v){
  return __uint_as_float(((unsigned)v)<<16);
}
__device__ __forceinline__ void gload16(const void* g, void* l){
  __builtin_amdgcn_global_load_lds((const __attribute__((address_space(1))) void*)g,
                                   (__attribute__((address_space(3))) void*)l, 16, 0, 0);
}

// ---------------- MFMA core: 128x128 tile (4 waves), A[M][K] bf16, BT[N][K] bf16 ----
__device__ __forceinline__ void gemm_core(const ushortT* __restrict__ A, int ldA,
                                          const ushortT* __restrict__ B, int ldB,
                                          int m0, int n0, int kstart, int ksteps,
                                          ushortT* As, ushortT* Bs, f4 (&acc)[4][4]){
  const int t = threadIdx.x, w = t>>6, lane = t&63;
  const int wr = w>>1, wc = w&1;
  const int lrow = lane&15, quad = lane>>4;
  const int r0 = w*32;
  const int srow = lane>>3, schunk = (lane&7)*8;
  for (int ks = 0; ks < ksteps; ks++){
    const int kk0 = kstart + ks*64;
    __syncthreads();
    #pragma unroll
    for (int q=0;q<4;q++)
      gload16(A + (size_t)(m0 + r0 + q*8 + srow)*ldA + kk0 + schunk, As + (r0 + q*8)*64);
    #pragma unroll
    for (int q=0;q<4;q++)
      gload16(B + (size_t)(n0 + r0 + q*8 + srow)*ldB + kk0 + schunk, Bs + (r0 + q*8)*64);
    __syncthreads();
    #pragma unroll
    for (int kk=0;kk<2;kk++){
      s8 af[4], bfr[4];
      #pragma unroll
      for (int tm=0;tm<4;tm++)
        af[tm] = *(const s8*)(As + (wr*64 + tm*16 + lrow)*64 + kk*32 + quad*8);
      #pragma unroll
      for (int tn=0;tn<4;tn++)
        bfr[tn] = *(const s8*)(Bs + (wc*64 + tn*16 + lrow)*64 + kk*32 + quad*8);
      #pragma unroll
      for (int tm=0;tm<4;tm++)
        #pragma unroll
        for (int tn=0;tn<4;tn++)
          acc[tm][tn] = __builtin_amdgcn_mfma_f32_16x16x32_bf16(af[tm], bfr[tn], acc[tm][tn], 0,0,0);
    }
  }
}

// ---------------- setup kernels ----------------

__global__ __launch_bounds__(256) void k_zero(float* __restrict__ ws){
  int t = blockIdx.x*256 + threadIdx.x;
  if (t < BN) { ws[OFF_RSQX + t] = 0.f; ws[OFF_RSQZ + t] = 0.f; }
  if (t < 64) ws[OFF_SCAL + t] = 0.f;
}

__global__ __launch_bounds__(64) void k_sq_x(const float* __restrict__ x, float* __restrict__ ws){
  int row = blockIdx.x, t = threadIdx.x;
  const float* xr = x + (size_t)row*DXC;
  float s = 0.f;
  for (int k = t; k < DXC; k += 64) { float v = xr[k]; s += v*v; }
  s = wave_sum(s);
  if (t == 0) { ws[OFF_SQX + row] = s; atomicAdd(&ws[OFF_SCAL+8], s); }
}

__global__ __launch_bounds__(64) void k_sq_z(const float* __restrict__ z, float* __restrict__ ws){
  int row = blockIdx.x, t = threadIdx.x;
  float v = (t < DZC) ? z[(size_t)row*DZC + t] : 0.f;
  float s = wave_sum(v*v);
  if (t == 0) ws[OFF_SQZ + row] = s;
}

template<int D>
__global__ __launch_bounds__(64) void k_stats(const float* __restrict__ P,
                                              const float* __restrict__ sq,
                                              float* __restrict__ ws, int sumidx,
                                              float* __restrict__ rowsq){
  __shared__ __align__(16) float As[32][36];
  __shared__ __align__(16) float Bs[32][36];
  const int i0 = blockIdx.x*32, j0 = blockIdx.y*32;
  const int t = threadIdx.x, tr = t&7, tc = t>>3;
  float acc[4][4] = {};
  for (int k0 = 0; k0 < D; k0 += 32) {
    for (int l = t; l < 1024; l += 64) {
      const int rr = l>>5, cc = l&31;
      As[cc][rr] = P[(size_t)(i0+rr)*D + (k0+cc)];
      Bs[cc][rr] = P[(size_t)(j0+rr)*D + (k0+cc)];
    }
    __syncthreads();
    #pragma unroll
    for (int kk = 0; kk < 32; kk++) {
      float a[4], b[4];
      *(float4*)a = *(const float4*)&As[kk][tr*4];
      *(float4*)b = *(const float4*)&Bs[kk][tc*4];
      fma16(acc, a, b);
    }
    __syncthreads();
  }
  float sqi[4], sqj[4];
  #pragma unroll
  for (int m=0;m<4;m++) sqi[m] = sq[i0+tr*4+m];
  #pragma unroll
  for (int n=0;n<4;n++) sqj[n] = sq[j0+tc*4+n];
  float tot = 0.f; float rs[4] = {0.f,0.f,0.f,0.f};
  #pragma unroll
  for (int m=0;m<4;m++)
    #pragma unroll
    for (int n=0;n<4;n++) {
      float raw = sqi[m] + sqj[n] - 2.f*acc[m][n];
      float cr = fmaxf(raw, 0.f);
      tot += cr;
      rs[m] += cr*cr;
    }
  float v = wave_sum(tot);
  if (t==0) atomicAdd(&ws[OFF_SCAL+sumidx], v);
  #pragma unroll
  for (int m=0;m<4;m++){
    float x2 = rs[m];
    x2 += __shfl_down(x2,32); x2 += __shfl_down(x2,16); x2 += __shfl_down(x2,8);
    if (tc==0) atomicAdd(&rowsq[i0+tr*4+m], x2);
  }
}

__global__ __launch_bounds__(256) void k_s3(const float* __restrict__ z, float* __restrict__ ws){
  int j = blockIdx.x*256 + threadIdx.x;
  float mx = ws[OFF_SCAL+0] / ((float)BN*(float)BN);
  float sx = 1.f/(mx + 1e-8f);
  float mz = ws[OFF_SCAL+1] / ((float)BN*(float)BN);
  float sz = 1.f/(mz + 1e-8f);
  if (j == 0) { ws[OFF_SCAL+2] = sx; ws[OFF_SCAL+3] = sz; }
  if (j < BN) {
    float cx = ws[OFF_RSQX+j]*sx*sx*INV_B;
    float cz = ws[OFF_RSQZ+j]*sz*sz*INV_B;
    ws[OFF_CX+j] = cx; ws[OFF_CZ+j] = cz;
    atomicAdd(&ws[OFF_SCAL+4], cx);
    atomicAdd(&ws[OFF_SCAL+5], cz);
    ws[OFF_R+j] = INV_B; ws[OFF_C+j] = 1.f;
    float msx = ws[OFF_SCAL+8]*INV_B;
    ws[OFF_U6+j] = 1.f;
    ws[OFF_U7+j] = msx;
    ushortT* zb  = (ushortT*)(ws + OFF_ZB);
    ushortT* zTb = (ushortT*)(ws + OFF_ZTB);
    for (int m=0;m<DZC;m++){
      ushortT v = f2bf(z[(size_t)j*DZC + m]);
      zb[(size_t)j*DZC + m] = v;
      zTb[(size_t)m*BN + j] = v;
    }
    zTb[(size_t)64*BN + j] = 0x3F80;               // 1.0
    zTb[(size_t)65*BN + j] = f2bf(ws[OFF_SQZ+j]);  // sqz
    for (int m=66;m<128;m++) zTb[(size_t)m*BN + j] = 0;
  }
}

__global__ __launch_bounds__(256) void k_cvt_x(const float* __restrict__ x, float* __restrict__ ws){
  int idx = blockIdx.x*256 + threadIdx.x;
  ((ushortT*)(ws + OFF_XB))[idx] = f2bf(x[idx]);
}

__global__ __launch_bounds__(256) void k_fillKb(float* __restrict__ ws){
  size_t idx = (size_t)blockIdx.x*256 + threadIdx.x;
  uint4 v = {0x3F803F80u, 0x3F803F80u, 0x3F803F80u, 0x3F803F80u};
  ((uint4*)(ws + OFF_KB))[idx] = v;
}

// XT[k][i] = x[i][k] (f32 transpose, once)
__global__ __launch_bounds__(256) void k_xt(const float* __restrict__ x, float* __restrict__ ws){
  __shared__ float tr[32][65];
  const int i0 = blockIdx.x*64, k0 = blockIdx.y*32;
  const int t = threadIdx.x;
  #pragma unroll
  for (int s=0;s<8;s++){
    int idx = t + s*256; int il = idx>>5, kl = idx&31;
    tr[kl][il] = x[(size_t)(i0+il)*DXC + k0+kl];
  }
  __syncthreads();
  float* XT = ws + OFF_XT;
  #pragma unroll
  for (int s=0;s<8;s++){
    int idx = t + s*256; int kl = idx>>6, il = idx&63;
    XT[(size_t)(k0+kl)*BN + i0+il] = tr[kl][il];
  }
}

// initial xrbT = bf16(XT * INV_B); zero UTB rows 258..383
__global__ __launch_bounds__(256) void k_xr0(float* __restrict__ ws){
  int idx = blockIdx.x*256 + threadIdx.x;
  ((ushortT*)(ws + OFF_XRT))[idx] = f2bf(ws[OFF_XT + idx] * INV_B);
  if (idx < 126*BN)
    ((ushortT*)(ws + OFF_UTB))[(size_t)258*BN + idx] = 0;
}

// ---------------- per-iteration kernels ----------------

// k1: UPt[sp][k][j] = bf16( sum_{i in split} xrbT[k,i]*Kb[j,i] )
__global__ __launch_bounds__(256) void k1_mfma(float* __restrict__ ws){
  __shared__ __align__(16) ushortT As[128*64];
  __shared__ __align__(16) ushortT Bs[128*64];
  const int m0 = blockIdx.x*128, n0 = blockIdx.y*128, sp = blockIdx.z;
  f4 acc[4][4] = {};
  gemm_core((const ushortT*)(ws+OFF_XRT), BN, (const ushortT*)(ws+OFF_KB), BN,
            m0, n0, sp*256, 4, As, Bs, acc);
  ushortT* __restrict__ UPt = (ushortT*)(ws + OFF_UPT) + (size_t)sp*DXC*BN;
  const int t = threadIdx.x, w = t>>6, lane = t&63;
  const int wr = w>>1, wc = w&1, lrow = lane&15, quad = lane>>4;
  #pragma unroll
  for (int tm=0;tm<4;tm++)
    #pragma unroll
    for (int tn=0;tn<4;tn++)
      #pragma unroll
      for (int rg=0;rg<4;rg++)
        UPt[(size_t)(m0+wr*64+tm*16+quad*4+rg)*BN + n0+wc*64+tn*16+lrow] = f2bf(acc[tm][tn][rg]);
}

// k1_red: UTB[k][j] (258 rows: 0..255 = c_j*sum_sp UPt, 256=u6, 257=u7); zero RMX + ACC
__global__ __launch_bounds__(256) void k1_red(float* __restrict__ ws){
  int tid = blockIdx.x*256 + threadIdx.x;
  if (tid < BN) ((unsigned*)(ws + OFF_RMX))[tid] = 0u;
  if (tid < 5*4*BN) ws[OFF_ACC + tid] = 0.f;
  if (tid >= 258*BN) return;
  int k = tid >> 11, j = tid & (BN-1);
  ushortT* __restrict__ UTB = (ushortT*)(ws + OFF_UTB);
  if (k < 256){
    const ushortT* __restrict__ UPt = (const ushortT*)(ws + OFF_UPT);
    float s = 0.f;
    #pragma unroll
    for (int sp=0;sp<8;sp++) s += bf2f(UPt[(size_t)sp*DXC*BN + tid]);
    UTB[tid] = f2bf(s * ws[OFF_C + j]);
  } else if (k == 256) UTB[tid] = f2bf(ws[OFF_U6 + j]);
  else                 UTB[tid] = f2bf(ws[OFF_U7 + j]);
}

// kW: WTP[sp][m][kc] = sum_{j in split} zTb[m,j]*UTB[kc,j]
__global__ __launch_bounds__(256) void kW_mfma(float* __restrict__ ws){
  __shared__ __align__(16) ushortT As[128*64];
  __shared__ __align__(16) ushortT Bs[128*64];
  const int n0 = blockIdx.y*128, sp = blockIdx.z;
  f4 acc[4][4] = {};
  gemm_core((const ushortT*)(ws+OFF_ZTB), BN, (const ushortT*)(ws+OFF_UTB), BN,
            0, n0, sp*512, 8, As, Bs, acc);
  float* __restrict__ WTP = ws + OFF_WTP + (size_t)sp*128*384;
  const int t = threadIdx.x, w = t>>6, lane = t&63;
  const int wr = w>>1, wc = w&1, lrow = lane&15, quad = lane>>4;
  #pragma unroll
  for (int tm=0;tm<4;tm++)
    #pragma unroll
    for (int tn=0;tn<4;tn++)
      #pragma unroll
      for (int rg=0;rg<4;rg++)
        WTP[(size_t)(wr*64+tm*16+quad*4+rg)*384 + n0+wc*64+tn*16+lrow] = acc[tm][tn][rg];
}

// kWred: Wtb bf16 (k<256), A6/A7 f32 (k=256/257)
__global__ __launch_bounds__(256) void kW_red(float* __restrict__ ws){
  int idx = blockIdx.x*256 + threadIdx.x;   // < 128*384
  int m = idx / 384, k = idx - m*384;
  if (k >= 258) return;
  float s = 0.f;
  #pragma unroll
  for (int sp=0;sp<4;sp++) s += ws[OFF_WTP + (size_t)sp*128*384 + idx];
  if (k < 256)      ((ushortT*)(ws + OFF_WTB))[idx] = f2bf(s);
  else if (k == 256) ws[OFF_A6 + m] = s;
  else               ws[OFF_A7 + m] = s;
}

// kV: V[i][m] = sx*(sqx_i*A6[m] + A7[m] - 2*sum_k xb[i,k]*Wtb[m,k])
__global__ __launch_bounds__(256) void kV_mfma(float* __restrict__ ws){
  __shared__ __align__(16) ushortT As[128*64];
  __shared__ __align__(16) ushortT Bs[128*64];
  const int m0 = blockIdx.x*128;
  f4 acc[4][4] = {};
  gemm_core((const ushortT*)(ws+OFF_XB), DXC, (const ushortT*)(ws+OFF_WTB), 384,
            m0, 0, 0, 4, As, Bs, acc);
  const float sx = ws[OFF_SCAL+2];
  const int t = threadIdx.x, w = t>>6, lane = t&63;
  const int wr = w>>1, wc = w&1, lrow = lane&15, quad = lane>>4;
  ushortT* __restrict__ Vb = (ushortT*)(ws + OFF_VB);
  #pragma unroll
  for (int tn=0;tn<4;tn++){
    const int m = wc*64 + tn*16 + lrow;
    if (m < 66){
      const float a6 = ws[OFF_A6+m], a7 = ws[OFF_A7+m];
      #pragma unroll
      for (int tm=0;tm<4;tm++)
        #pragma unroll
        for (int rg=0;rg<4;rg++){
          const int i = m0 + wr*64 + tm*16 + quad*4 + rg;
          float V = sx*(ws[OFF_SQX+i]*a6 + a7 - 2.f*acc[tm][tn][rg]);
          if (m < 64)       Vb[(size_t)i*64 + m] = f2bf(V);
          else if (m == 64) ws[OFF_V64 + i] = V;
          else              ws[OFF_V65 + i] = V;
        }
    }
  }
}

// k4: cross GEMM. mode 0: row-max of expo only. mode 1: final cross_term.
__global__ __launch_bounds__(256) void k4_mfma(float* __restrict__ ws, int final_pass){
  __shared__ __align__(16) ushortT As[128*64];
  __shared__ __align__(16) ushortT Bs[128*64];
  const int m0 = blockIdx.x*128, n0 = blockIdx.y*128;   // m=j, n=i
  f4 acc[4][4] = {};
  gemm_core((const ushortT*)(ws+OFF_ZB), DZC, (const ushortT*)(ws+OFF_VB), DZC,
            m0, n0, 0, 1, As, Bs, acc);
  const float sz = ws[OFF_SCAL+3];
  const int t = threadIdx.x, w = t>>6, lane = t&63;
  const int wr = w>>1, wc = w&1, lrow = lane&15, quad = lane>>4;
  if (!final_pass){
    unsigned* __restrict__ rmx = (unsigned*)(ws + OFF_RMX);
    #pragma unroll
    for (int tn=0;tn<4;tn++){
      const int i = n0 + wc*64 + tn*16 + lrow;
      const float v64 = ws[OFF_V64+i], v65 = ws[OFF_V65+i], cx = ws[OFF_CX+i];
      float mx = -3.4e38f;
      #pragma unroll
      for (int tm=0;tm<4;tm++)
        #pragma unroll
        for (int rg=0;rg<4;rg++){
          const int j = m0 + wr*64 + tm*16 + quad*4 + rg;
          float cross = sz*(v65 + v64*ws[OFF_SQZ+j] - 2.f*acc[tm][tn][rg]);
          float expo = 2.f*cross - cx - ws[OFF_CZ+j];
          mx = fmaxf(mx, expo);
        }
      mx = fmaxf(mx, __shfl_down(mx,32));
      mx = fmaxf(mx, __shfl_down(mx,16));
      if (quad == 0) atomicMax(&rmx[i], encf(mx));
    }
  } else {
    const ushortT* __restrict__ Kb = (const ushortT*)(ws + OFF_KB);
    float s = 0.f;
    #pragma unroll
    for (int tn=0;tn<4;tn++){
      const int i = n0 + wc*64 + tn*16 + lrow;
      const float v64 = ws[OFF_V64+i], v65 = ws[OFF_V65+i], ri = ws[OFF_R+i];
      #pragma unroll
      for (int tm=0;tm<4;tm++)
        #pragma unroll
        for (int rg=0;rg<4;rg++){
          const int j = m0 + wr*64 + tm*16 + quad*4 + rg;
          float cross = sz*(v65 + v64*ws[OFF_SQZ+j] - 2.f*acc[tm][tn][rg]);
          float tij = ri * bf2f(Kb[(size_t)j*BN + i]) * ws[OFF_C+j];
          s += cross*tij;
        }
    }
    s = wave_sum(s);
    if (lane == 0) atomicAdd(&ws[OFF_SCAL+6], s);
  }
}

// k5: recompute cross GEMM, Kb=bf16(exp(expo-M_i)), rowsum atomicAdd -> ACC[0]
__global__ __launch_bounds__(256) void k5_exp(float* __restrict__ ws){
  __shared__ __align__(16) ushortT As[128*64];
  __shared__ __align__(16) ushortT Bs[128*64];
  const int m0 = blockIdx.x*128, n0 = blockIdx.y*128;
  f4 acc[4][4] = {};
  gemm_core((const ushortT*)(ws+OFF_ZB), DZC, (const ushortT*)(ws+OFF_VB), DZC,
            m0, n0, 0, 1, As, Bs, acc);
  const float sz = ws[OFF_SCAL+3];
  const int t = threadIdx.x, w = t>>6, lane = t&63;
  const int wr = w>>1, wc = w&1, lrow = lane&15, quad = lane>>4;
  const int aln = (blockIdx.y*16 + blockIdx.x)&3;
  ushortT* __restrict__ Kb = (ushortT*)(ws + OFF_KB);
  const unsigned* __restrict__ rmx = (const unsigned*)(ws + OFF_RMX);
  #pragma unroll
  for (int tn=0;tn<4;tn++){
    const int i = n0 + wc*64 + tn*16 + lrow;
    const float v64 = ws[OFF_V64+i], v65 = ws[OFF_V65+i], cx = ws[OFF_CX+i];
    const float Mi = decf(rmx[i]);
    float s = 0.f;
    #pragma unroll
    for (int tm=0;tm<4;tm++)
      #pragma unroll
      for (int rg=0;rg<4;rg++){
        const int j = m0 + wr*64 + tm*16 + quad*4 + rg;
        float cross = sz*(v65 + v64*ws[OFF_SQZ+j] - 2.f*acc[tm][tn][rg]);
        float expo = 2.f*cross - cx - ws[OFF_CZ+j];
        ushortT vv = f2bf(__expf(expo - Mi));
        Kb[(size_t)j*BN + i] = vv;
        s += bf2f(vv);
      }
    s += __shfl_down(s,32);
    s += __shfl_down(s,16);
    if (quad == 0) atomicAdd(&ws[OFF_ACC + (size_t)aln*BN + i], s);
  }
}

// k_cr round n (0..4): rv from ACC[n] (+R prev slot), c-update local (block owns rows j0..j0+7),
// n<4: r-partials atomicAdd -> ACC[n+1], block0 publishes r_n to R slot n&1.
// n==4: C/U6/U7 + XRT row write + R slot0.
__global__ __launch_bounds__(256) void k_cr(float* __restrict__ ws, int n){
  __shared__ float red1[8*256];
  __shared__ float red2[8*256];
  __shared__ float ccs[8];
  const int bid = blockIdx.x, t = threadIdx.x;
  const int j0 = bid*8, aln = bid&3;
  const float* __restrict__ ACCn = ws + OFF_ACC + (size_t)n*4*BN;
  float rv[8];
  #pragma unroll
  for (int q=0;q<8;q++){
    int i = t + q*256;
    float s0 = ACCn[i] + ACCn[BN+i] + ACCn[2*BN+i] + ACCn[3*BN+i];
    if (n == 0) rv[q] = INV_B/(s0 + 1e-8f);
    else {
      float rp = ws[OFF_R + ((n+1)&1)*BN + i];
      rv[q] = rp*INV_B/(rp*s0 + 1e-8f);
    }
  }
  float v[8][8];
  {
    const ushortT* __restrict__ Kbp = (const ushortT*)(ws + OFF_KB);
    #pragma unroll
    for (int jj=0;jj<8;jj++)
      #pragma unroll
      for (int q=0;q<8;q++)
        v[jj][q] = bf2f(Kbp[(size_t)(j0+jj)*BN + t + q*256]);
  }
  const int last = (n == 4);
  #pragma unroll
  for (int jj=0;jj<8;jj++){
    float s1 = 0.f, s2 = 0.f;
    if (last){
      #pragma unroll
      for (int q=0;q<8;q++){ float kv = v[jj][q]*rv[q]; s1 += kv; s2 += kv*ws[OFF_SQX + t+q*256]; }
    } else {
      #pragma unroll
      for (int q=0;q<8;q++) s1 += v[jj][q]*rv[q];
    }
    red1[jj*256 + t] = s1;
    red2[jj*256 + t] = s2;
  }
  __syncthreads();
  const int g = t>>5, l = t&31;
  float a = 0.f, b = 0.f;
  #pragma unroll
  for (int k=0;k<8;k++) a += red1[g*256 + l + k*32];
  if (last)
    #pragma unroll
    for (int k=0;k<8;k++) b += red2[g*256 + l + k*32];
  #pragma unroll
  for (int o=16;o;o>>=1){
    a += __shfl_xor(a, o);
    if (last) b += __shfl_xor(b, o);
  }
  if (l == 0){
    const int j = j0 + g;
    float cn;
    if (n == 0) cn = INV_B/(a + 1e-8f);
    else { float cj = ws[OFF_C+j]; cn = cj*INV_B/(cj*a + 1e-8f); }
    ws[OFF_C+j] = cn;
    ccs[g] = cn;
    if (last){ ws[OFF_U6+j] = cn*a; ws[OFF_U7+j] = cn*b; }
  }
  __syncthreads();
  if (!last){
    float cl[8];
    #pragma unroll
    for (int jj=0;jj<8;jj++) cl[jj] = ccs[jj];
    const size_t ro = OFF_ACC + (size_t)((n+1)*4 + aln)*BN;
    #pragma unroll
    for (int q=0;q<8;q++){
      float p = 0.f;
      #pragma unroll
      for (int jj=0;jj<8;jj++) p += v[jj][q]*cl[jj];
      atomicAdd(&ws[ro + t + q*256], p);
    }
    if (bid == 0){
      #pragma unroll
      for (int q=0;q<8;q++) ws[OFF_R + (size_t)(n&1)*BN + t + q*256] = rv[q];
    }
  } else {
    const float* __restrict__ XTp = ws + OFF_XT + (size_t)bid*BN;
    ushortT* __restrict__ XRT = (ushortT*)(ws + OFF_XRT) + (size_t)bid*BN;
    #pragma unroll
    for (int q=0;q<8;q++) XRT[t + q*256] = f2bf(XTp[t + q*256]*rv[q]);
    if (bid == 0){
      #pragma unroll
      for (int q=0;q<8;q++) ws[OFF_R + t + q*256] = rv[q];   // slot 0 (4&1==0)
    }
  }
}

// ---------------- reg loss + finalize ----------------

__global__ __launch_bounds__(64) void k_reg(const float* __restrict__ z, const float* __restrict__ y,
                                            float* __restrict__ ws){
  __shared__ __align__(16) float As[32][36];
  __shared__ __align__(16) float Bs[32][36];
  const int i0 = blockIdx.x*32, j0 = blockIdx.y*32;
  const int t = threadIdx.x, tr = t&7, tc = t>>3;
  float acc[4][4] = {};
  for (int k0=0; k0<DZC; k0+=32){
    for (int l=t;l<1024;l+=64){
      const int rr=l>>5, cc=l&31;
      As[cc][rr] = z[(size_t)(i0+rr)*DZC + (k0+cc)];
      Bs[cc][rr] = z[(size_t)(j0+rr)*DZC + (k0+cc)];
    }
    __syncthreads();
    #pragma unroll
    for (int kk=0;kk<32;kk++){
      float a[4], b[4];
      *(float4*)a = *(const float4*)&As[kk][tr*4];
      *(float4*)b = *(const float4*)&Bs[kk][tc*4];
      fma16(acc, a, b);
    }
    __syncthreads();
  }
  const float sz = ws[OFF_SCAL+3];
  float sqi[4], yi[4];
  #pragma unroll
  for (int m=0;m<4;m++){ int i=i0+tr*4+m; sqi[m]=ws[OFF_SQZ+i]; yi[m]=y[i]; }
  float sqj[4], yj[4];
  #pragma unroll
  for (int n=0;n<4;n++){ int j=j0+tc*4+n; sqj[n]=ws[OFF_SQZ+j]; yj[n]=y[j]; }
  float s = 0.f;
  #pragma unroll
  for (int m=0;m<4;m++)
    #pragma unroll
    for (int n=0;n<4;n++){
      int i = i0+tr*4+m, j = j0+tc*4+n;
      float raw = sqi[m] + sqj[n] - 2.f*acc[m][n];
      float cz = sz*fmaxf(raw, 0.f);
      float zd = fmaxf(cz, 1e-4f);
      float d = logf(fabsf(yi[m]-yj[n]) + 1e-6f) - logf(zd + 1e-6f);
      if (i != j) s += d*d;
    }
  s = wave_sum(s);
  if (t==0) atomicAdd(&ws[OFF_SCAL+7], s);
}

__global__ void k_finalize(float* __restrict__ ws, float* __restrict__ out){
  float gw = ws[OFF_SCAL+4]*INV_B + ws[OFF_SCAL+5]*INV_B - 2.f*ws[OFF_SCAL+6];
  gw = fmaxf(gw, 0.f);
  float reg = ws[OFF_SCAL+7] / ((float)BN*(float)(BN-1));
  out[0] = gw + reg;
}

// ---------------- host ----------------

extern "C" void kernel_launch(void* const* d_in, const int* in_sizes, int n_in,
                              void* d_out, int out_size, void* d_ws, size_t ws_size,
                              hipStream_t stream){
  (void)in_sizes; (void)n_in; (void)out_size; (void)ws_size;
  const float* x = (const float*)d_in[0];
  const float* z = (const float*)d_in[1];
  const float* y = (const float*)d_in[2];
  float* out = (float*)d_out;
  float* ws = (float*)d_ws;

  hipLaunchKernelGGL(k_zero, dim3(8), dim3(256), 0, stream, ws);
  hipLaunchKernelGGL(k_sq_x, dim3(BN), dim3(64), 0, stream, x, ws);
  hipLaunchKernelGGL(k_sq_z, dim3(BN), dim3(64), 0, stream, z, ws);
  hipLaunchKernelGGL(HIP_KERNEL_NAME(k_stats<DXC>), dim3(64,64), dim3(64), 0, stream,
                     x, ws+OFF_SQX, ws, 0, ws+OFF_RSQX);
  hipLaunchKernelGGL(HIP_KERNEL_NAME(k_stats<DZC>), dim3(64,64), dim3(64), 0, stream,
                     z, ws+OFF_SQZ, ws, 1, ws+OFF_RSQZ);
  hipLaunchKernelGGL(k_s3, dim3(8), dim3(256), 0, stream, z, ws);
  hipLaunchKernelGGL(k_cvt_x, dim3(2048), dim3(256), 0, stream, x, ws);
  hipLaunchKernelGGL(k_fillKb, dim3(2048), dim3(256), 0, stream, ws);
  hipLaunchKernelGGL(k_xt, dim3(32,8), dim3(256), 0, stream, x, ws);
  hipLaunchKernelGGL(k_xr0, dim3(2048), dim3(256), 0, stream, ws);

  for (int it = 0; it < NITER; it++){
    hipLaunchKernelGGL(k1_mfma, dim3(2,16,8), dim3(256), 0, stream, ws);
    hipLaunchKernelGGL(k1_red, dim3(2080), dim3(256), 0, stream, ws);
    hipLaunchKernelGGL(kW_mfma, dim3(1,3,4), dim3(256), 0, stream, ws);
    hipLaunchKernelGGL(kW_red, dim3(192), dim3(256), 0, stream, ws);
    hipLaunchKernelGGL(kV_mfma, dim3(16), dim3(256), 0, stream, ws);
    hipLaunchKernelGGL(k4_mfma, dim3(16,16), dim3(256), 0, stream, ws, 0);
    hipLaunchKernelGGL(k5_exp, dim3(16,16), dim3(256), 0, stream, ws);
    for (int n = 0; n < 5; n++)
      hipLaunchKernelGGL(k_cr, dim3(256), dim3(256), 0, stream, ws, n);
  }

  // final evaluation with converged T = diag(r) Kb diag(c)
  hipLaunchKernelGGL(k1_mfma, dim3(2,16,8), dim3(256), 0, stream, ws);
  hipLaunchKernelGGL(k1_red, dim3(2080), dim3(256), 0, stream, ws);
  hipLaunchKernelGGL(kW_mfma, dim3(1,3,4), dim3(256), 0, stream, ws);
  hipLaunchKernelGGL(kW_red, dim3(192), dim3(256), 0, stream, ws);
  hipLaunchKernelGGL(kV_mfma, dim3(16), dim3(256), 0, stream, ws);
  hipLaunchKernelGGL(k4_mfma, dim3(16,16), dim3(256), 0, stream, ws, 1);

  hipLaunchKernelGGL(k_reg, dim3(64,64), dim3(64), 0, stream, z, y, ws);
  hipLaunchKernelGGL(k_finalize, dim3(1), dim3(1), 0, stream, ws, out);
}